// Round 2
// 310.467 us; speedup vs baseline: 1.1097x; 1.1097x over previous
//
#include <hip/hip_runtime.h>

#define N3   (64*64*64)      // 262144
#define NO   70
#define NO2  (NO*NO)         // 4900
#define NO3  (NO*NO*NO)      // 343000
#define OH   (2*NO3)         // 686000  (h output elements)
#define SZ   (2*16*N3)       // 8388608 (each [B,16,D,H,W] output)
#define NBI  512             // interior blocks: 2*64*64*16 threads / 256

typedef float f32x4 __attribute__((ext_vector_type(4)));

__device__ __forceinline__ float relu(float x){ return x > 0.f ? x : 0.f; }

__global__ __launch_bounds__(256) void ham_fused(
    const float* __restrict__ p, const float* __restrict__ q,
    const float* __restrict__ W1, const float* __restrict__ b1,
    const float* __restrict__ W2, const float* __restrict__ b2,
    const float* __restrict__ W3, const float* __restrict__ b3p,
    float* __restrict__ out)
{
    // ---- stage folded weights into LDS (uniform-broadcast reads later) ----
    __shared__ float WpT[16][16];   // W1[:,0:16]  transposed -> [c][o]
    __shared__ float WqT[16][16];   // W1[:,48:64] transposed -> [c][o]
    __shared__ float W2l[16][16];   // W2[o][c]
    __shared__ float b1l[16], b2l[16], W3l[16];
    __shared__ float s1x[16], s1y[16], s2x[16], s2y[16]; // W1 column-group sums

    int t = threadIdx.x;
    {
        int o = t >> 4, c = t & 15;
        WpT[c][o] = W1[o*96 + c];
        WqT[c][o] = W1[o*96 + 48 + c];
        W2l[o][c] = W2[o*16 + c];
    }
    if (t < 16) {
        b1l[t] = b1[t]; b2l[t] = b2[t]; W3l[t] = W3[t];
        float ax=0.f, ay=0.f, bx=0.f, by=0.f;
        #pragma unroll
        for (int j = 0; j < 16; ++j) {
            ax += W1[t*96 + 16 + j];
            ay += W1[t*96 + 32 + j];
            bx += W1[t*96 + 64 + j];
            by += W1[t*96 + 80 + j];
        }
        s1x[t]=ax; s1y[t]=ay; s2x[t]=bx; s2y[t]=by;
    }
    __syncthreads();
    float b3v = b3p[0];

    if (blockIdx.x >= NBI) {
        // ---- boundary shell of the 70^3 h grid: one of 3 bias constants ----
        int idx = (blockIdx.x - NBI)*256 + t;
        if (idx >= OH) return;
        int b = idx / NO3;
        int r = idx - b*NO3;
        int d = r / NO2; r -= d*NO2;
        int h = r / NO;
        int w = r - h*NO;
        int m = min(min(min(d,69-d), min(h,69-h)), min(w,69-w));
        if (m >= 3) return;             // interior handled by interior blocks
        float v;
        if (m == 0) {
            v = relu(b3v);
        } else if (m == 1) {
            float a = b3v;
            #pragma unroll
            for (int o = 0; o < 16; ++o) a += W3l[o]*relu(b2l[o]);
            v = relu(a);
        } else {
            float a = b3v;
            #pragma unroll
            for (int o = 0; o < 16; ++o) {
                float s = b2l[o];
                #pragma unroll
                for (int c = 0; c < 16; ++c) s += W2l[o][c]*relu(b1l[c]);
                a += W3l[o]*relu(s);
            }
            v = relu(a);
        }
        out[idx] = v;
        return;
    }

    // ---- interior: one thread = 4 consecutive w voxels of the 64^3 grid ----
    int tid = blockIdx.x*256 + t;
    int w0 = (tid & 15) << 2;        // 0,4,...,60  (16B-aligned)
    int h0 = (tid >> 4) & 63;
    int d0 = (tid >> 10) & 63;
    int b  = tid >> 16;

    const float* ps = p + (b*16 + 1)*N3;   // channel 1 slabs
    const float* qs = q + (b*16 + 1)*N3;

    // central-difference row: g[j] = 0.5*(s[w0+j+1]-s[w0+j-1]), zero-padded
    auto grow = [&](const float* s, int dd, int hh, float g[4]) {
        if ((unsigned)dd >= 64u || (unsigned)hh >= 64u) {
            g[0]=g[1]=g[2]=g[3]=0.f; return;
        }
        const float* r = s + dd*4096 + hh*64 + w0;
        f32x4 v = *reinterpret_cast<const f32x4*>(r);
        float lft = (w0 > 0)  ? r[-1] : 0.f;
        float rgt = (w0 < 60) ? r[4]  : 0.f;
        g[0] = 0.5f*(v.y - lft);
        g[1] = 0.5f*(v.z - v.x);
        g[2] = 0.5f*(v.w - v.y);
        g[3] = 0.5f*(rgt - v.z);
    };

    float gp_c[4], gp_a[4], gp_b[4], gp_e[4], gp_f[4];
    float gq_c[4], gq_a[4], gq_b[4], gq_e[4], gq_f[4];
    grow(ps, d0,   h0,   gp_c);
    grow(ps, d0-1, h0,   gp_a);
    grow(ps, d0+1, h0,   gp_b);
    grow(ps, d0,   h0-1, gp_e);
    grow(ps, d0,   h0+1, gp_f);
    grow(qs, d0,   h0,   gq_c);
    grow(qs, d0-1, h0,   gq_a);
    grow(qs, d0+1, h0,   gq_b);
    grow(qs, d0,   h0-1, gq_e);
    grow(qs, d0,   h0+1, gq_f);

    float dpx[4], dpy[4], dqx[4], dqy[4];
    #pragma unroll
    for (int j = 0; j < 4; ++j) {
        dpx[j] = gp_a[j] + gp_c[j] + gp_b[j];
        dpy[j] = gp_e[j] + gp_c[j] + gp_f[j];
        dqx[j] = gq_a[j] + gq_c[j] + gq_b[j];
        dqy[j] = gq_e[j] + gq_c[j] + gq_f[j];
    }

    // layer-1 accumulator, gradient terms folded via column-group sums
    float y1[16][4];
    #pragma unroll
    for (int o = 0; o < 16; ++o) {
        #pragma unroll
        for (int j = 0; j < 4; ++j)
            y1[o][j] = b1l[o] + s1x[o]*dpx[j] + s1y[o]*dpy[j]
                              + s2x[o]*dqx[j] + s2y[o]*dqy[j];
    }

    int sbase = d0*4096 + h0*64 + w0;
    int ibase = b*16*N3 + sbase;               // < 2^23, int is fine

    float* outp  = out + OH;
    float* outdx = out + OH + SZ;
    float* outdy = out + OH + 2*SZ;
    float* outq  = out + OH + 3*SZ;
    float* outqx = out + OH + 4*SZ;
    float* outqy = out + OH + 5*SZ;

    // channel loop: f32x4 loads, f32x4 nontemporal passthrough stores, FMA
    #pragma unroll 4
    for (int c = 0; c < 16; ++c) {
        f32x4 pc = __builtin_nontemporal_load(
                        reinterpret_cast<const f32x4*>(p + ibase + c*N3));
        f32x4 qc = __builtin_nontemporal_load(
                        reinterpret_cast<const f32x4*>(q + ibase + c*N3));
        __builtin_nontemporal_store(pc, reinterpret_cast<f32x4*>(outp + ibase + c*N3));
        __builtin_nontemporal_store(qc, reinterpret_cast<f32x4*>(outq + ibase + c*N3));
        #pragma unroll
        for (int o = 0; o < 16; ++o) {
            float wp = WpT[c][o], wq = WqT[c][o];
            y1[o][0] += wp*pc.x + wq*qc.x;
            y1[o][1] += wp*pc.y + wq*qc.y;
            y1[o][2] += wp*pc.z + wq*qc.z;
            y1[o][3] += wp*pc.w + wq*qc.w;
        }
    }

    // channel-broadcast gradient outputs, f32x4 nontemporal
    f32x4 vdpx = { dpx[0], dpx[1], dpx[2], dpx[3] };
    f32x4 vdpy = { dpy[0], dpy[1], dpy[2], dpy[3] };
    f32x4 vdqx = { dqx[0], dqx[1], dqx[2], dqx[3] };
    f32x4 vdqy = { dqy[0], dqy[1], dqy[2], dqy[3] };
    #pragma unroll 4
    for (int c = 0; c < 16; ++c) {
        __builtin_nontemporal_store(vdpx, reinterpret_cast<f32x4*>(outdx + ibase + c*N3));
        __builtin_nontemporal_store(vdpy, reinterpret_cast<f32x4*>(outdy + ibase + c*N3));
        __builtin_nontemporal_store(vdqx, reinterpret_cast<f32x4*>(outqx + ibase + c*N3));
        __builtin_nontemporal_store(vdqy, reinterpret_cast<f32x4*>(outqy + ibase + c*N3));
    }

    #pragma unroll
    for (int o = 0; o < 16; ++o) {
        #pragma unroll
        for (int j = 0; j < 4; ++j) y1[o][j] = relu(y1[o][j]);
    }

    // layers 2+3, per voxel
    int hbase = b*NO3 + (d0+3)*NO2 + (h0+3)*NO + (w0+3);
    #pragma unroll
    for (int j = 0; j < 4; ++j) {
        float a = b3v;
        #pragma unroll
        for (int o = 0; o < 16; ++o) {
            float s = b2l[o];
            #pragma unroll
            for (int c = 0; c < 16; ++c) s += W2l[o][c]*y1[c][j];
            a += W3l[o]*relu(s);
        }
        out[hbase + j] = relu(a);
    }
}

extern "C" void kernel_launch(void* const* d_in, const int* in_sizes, int n_in,
                              void* d_out, int out_size, void* d_ws, size_t ws_size,
                              hipStream_t stream) {
    const float* p  = (const float*)d_in[0];
    const float* q  = (const float*)d_in[1];
    const float* W1 = (const float*)d_in[2];
    const float* b1 = (const float*)d_in[3];
    const float* W2 = (const float*)d_in[4];
    const float* b2 = (const float*)d_in[5];
    const float* W3 = (const float*)d_in[6];
    const float* b3 = (const float*)d_in[7];
    float* out = (float*)d_out;

    int bBoundary = (OH + 255) / 256;        // 2680
    int blocks = NBI + bBoundary;            // 512 interior + boundary fill
    ham_fused<<<blocks, 256, 0, stream>>>(p, q, W1, b1, W2, b2, W3, b3, out);
}

// Round 4
// 308.279 us; speedup vs baseline: 1.1176x; 1.0071x over previous
//
#include <hip/hip_runtime.h>

#define N3   (64*64*64)      // 262144
#define NO   70
#define NO2  (NO*NO)         // 4900
#define NO3  (NO*NO*NO)      // 343000
#define OH   (2*NO3)         // 686000  (h output elements)
#define SZ   (2*16*N3)       // 8388608 (each [B,16,D,H,W] output)
#define NBI  512             // interior blocks: 2*64*64*16 threads / 256

typedef float f32x4 __attribute__((ext_vector_type(4)));

__device__ __forceinline__ float relu(float x){ return x > 0.f ? x : 0.f; }

__global__ __launch_bounds__(256) void ham_fused(
    const float* __restrict__ p, const float* __restrict__ q,
    const float* __restrict__ W1, const float* __restrict__ b1,
    const float* __restrict__ W2, const float* __restrict__ b2,
    const float* __restrict__ W3, const float* __restrict__ b3p,
    float* __restrict__ out)
{
    // ---- stage folded weights into LDS (uniform-broadcast reads later) ----
    __shared__ float WpT[16][16];   // W1[:,0:16]  transposed -> [c][o]
    __shared__ float WqT[16][16];   // W1[:,48:64] transposed -> [c][o]
    __shared__ float W2l[16][16];   // W2[o][c]
    __shared__ float b1l[16], b2l[16], W3l[16];
    __shared__ float s1x[16], s1y[16], s2x[16], s2y[16]; // W1 column-group sums

    int t = threadIdx.x;
    {
        int o = t >> 4, c = t & 15;
        WpT[c][o] = W1[o*96 + c];
        WqT[c][o] = W1[o*96 + 48 + c];
        W2l[o][c] = W2[o*16 + c];
    }
    if (t < 16) {
        b1l[t] = b1[t]; b2l[t] = b2[t]; W3l[t] = W3[t];
        float ax=0.f, ay=0.f, bx=0.f, by=0.f;
        #pragma unroll
        for (int j = 0; j < 16; ++j) {
            ax += W1[t*96 + 16 + j];
            ay += W1[t*96 + 32 + j];
            bx += W1[t*96 + 64 + j];
            by += W1[t*96 + 80 + j];
        }
        s1x[t]=ax; s1y[t]=ay; s2x[t]=bx; s2y[t]=by;
    }
    __syncthreads();
    float b3v = b3p[0];

    if (blockIdx.x >= NBI) {
        // ---- boundary shell of the 70^3 h grid: one of 3 bias constants ----
        int idx = (blockIdx.x - NBI)*256 + t;
        if (idx >= OH) return;
        int b = idx / NO3;
        int r = idx - b*NO3;
        int d = r / NO2; r -= d*NO2;
        int h = r / NO;
        int w = r - h*NO;
        int m = min(min(min(d,69-d), min(h,69-h)), min(w,69-w));
        if (m >= 3) return;             // interior handled by interior blocks
        // thread-invariant values: compute uniformly (no divergence cost)
        float v0 = relu(b3v);
        float v1 = b3v;
        float v2 = b3v;
        #pragma unroll
        for (int o = 0; o < 16; ++o) {
            v1 += W3l[o]*relu(b2l[o]);
            float s = b2l[o];
            #pragma unroll
            for (int c = 0; c < 16; ++c) s += W2l[o][c]*relu(b1l[c]);
            v2 += W3l[o]*relu(s);
        }
        v1 = relu(v1); v2 = relu(v2);
        out[idx] = (m == 0) ? v0 : (m == 1 ? v1 : v2);
        return;
    }

    // ---- interior: one thread = 4 consecutive w voxels of the 64^3 grid ----
    int tid = blockIdx.x*256 + t;
    int w0 = (tid & 15) << 2;        // 0,4,...,60  (16B-aligned)
    int h0 = (tid >> 4) & 63;
    int d0 = (tid >> 10) & 63;
    int b  = tid >> 16;

    const float* ps = p + (b*16 + 1)*N3;   // channel 1 slabs
    const float* qs = q + (b*16 + 1)*N3;

    // central-difference row: g[j] = 0.5*(s[w0+j+1]-s[w0+j-1]), zero-padded
    auto grow = [&](const float* s, int dd, int hh, float g[4]) {
        if ((unsigned)dd >= 64u || (unsigned)hh >= 64u) {
            g[0]=g[1]=g[2]=g[3]=0.f; return;
        }
        const float* r = s + dd*4096 + hh*64 + w0;
        f32x4 v = *reinterpret_cast<const f32x4*>(r);
        float lft = (w0 > 0)  ? r[-1] : 0.f;
        float rgt = (w0 < 60) ? r[4]  : 0.f;
        g[0] = 0.5f*(v.y - lft);
        g[1] = 0.5f*(v.z - v.x);
        g[2] = 0.5f*(v.w - v.y);
        g[3] = 0.5f*(rgt - v.z);
    };

    float gp_c[4], gp_a[4], gp_b[4], gp_e[4], gp_f[4];
    float gq_c[4], gq_a[4], gq_b[4], gq_e[4], gq_f[4];
    grow(ps, d0,   h0,   gp_c);
    grow(ps, d0-1, h0,   gp_a);
    grow(ps, d0+1, h0,   gp_b);
    grow(ps, d0,   h0-1, gp_e);
    grow(ps, d0,   h0+1, gp_f);
    grow(qs, d0,   h0,   gq_c);
    grow(qs, d0-1, h0,   gq_a);
    grow(qs, d0+1, h0,   gq_b);
    grow(qs, d0,   h0-1, gq_e);
    grow(qs, d0,   h0+1, gq_f);

    float dpx[4], dpy[4], dqx[4], dqy[4];
    #pragma unroll
    for (int j = 0; j < 4; ++j) {
        dpx[j] = gp_a[j] + gp_c[j] + gp_b[j];
        dpy[j] = gp_e[j] + gp_c[j] + gp_f[j];
        dqx[j] = gq_a[j] + gq_c[j] + gq_b[j];
        dqy[j] = gq_e[j] + gq_c[j] + gq_f[j];
    }

    // layer-1 accumulator, gradient terms folded via column-group sums
    float y1[16][4];
    #pragma unroll
    for (int o = 0; o < 16; ++o) {
        #pragma unroll
        for (int j = 0; j < 4; ++j)
            y1[o][j] = b1l[o] + s1x[o]*dpx[j] + s1y[o]*dpy[j]
                              + s2x[o]*dqx[j] + s2y[o]*dqy[j];
    }

    int sbase = d0*4096 + h0*64 + w0;
    int ibase = b*16*N3 + sbase;               // < 2^23, int is fine

    float* outp  = out + OH;
    float* outdx = out + OH + SZ;
    float* outdy = out + OH + 2*SZ;
    float* outq  = out + OH + 3*SZ;
    float* outqx = out + OH + 4*SZ;
    float* outqy = out + OH + 5*SZ;

    // channel loop: f32x4 loads, f32x4 nontemporal passthrough stores, FMA
    #pragma unroll 8
    for (int c = 0; c < 16; ++c) {
        f32x4 pc = __builtin_nontemporal_load(
                        reinterpret_cast<const f32x4*>(p + ibase + c*N3));
        f32x4 qc = __builtin_nontemporal_load(
                        reinterpret_cast<const f32x4*>(q + ibase + c*N3));
        __builtin_nontemporal_store(pc, reinterpret_cast<f32x4*>(outp + ibase + c*N3));
        __builtin_nontemporal_store(qc, reinterpret_cast<f32x4*>(outq + ibase + c*N3));
        #pragma unroll
        for (int o = 0; o < 16; ++o) {
            float wp = WpT[c][o], wq = WqT[c][o];
            y1[o][0] += wp*pc.x + wq*qc.x;
            y1[o][1] += wp*pc.y + wq*qc.y;
            y1[o][2] += wp*pc.z + wq*qc.z;
            y1[o][3] += wp*pc.w + wq*qc.w;
        }
    }

    // channel-broadcast gradient outputs, f32x4 nontemporal
    f32x4 vdpx = { dpx[0], dpx[1], dpx[2], dpx[3] };
    f32x4 vdpy = { dpy[0], dpy[1], dpy[2], dpy[3] };
    f32x4 vdqx = { dqx[0], dqx[1], dqx[2], dqx[3] };
    f32x4 vdqy = { dqy[0], dqy[1], dqy[2], dqy[3] };
    #pragma unroll
    for (int c = 0; c < 16; ++c) {
        __builtin_nontemporal_store(vdpx, reinterpret_cast<f32x4*>(outdx + ibase + c*N3));
        __builtin_nontemporal_store(vdpy, reinterpret_cast<f32x4*>(outdy + ibase + c*N3));
        __builtin_nontemporal_store(vdqx, reinterpret_cast<f32x4*>(outqx + ibase + c*N3));
        __builtin_nontemporal_store(vdqy, reinterpret_cast<f32x4*>(outqy + ibase + c*N3));
    }

    #pragma unroll
    for (int o = 0; o < 16; ++o) {
        #pragma unroll
        for (int j = 0; j < 4; ++j) y1[o][j] = relu(y1[o][j]);
    }

    // layers 2+3, per voxel
    int hbase = b*NO3 + (d0+3)*NO2 + (h0+3)*NO + (w0+3);
    #pragma unroll
    for (int j = 0; j < 4; ++j) {
        float a = b3v;
        #pragma unroll
        for (int o = 0; o < 16; ++o) {
            float s = b2l[o];
            #pragma unroll
            for (int c = 0; c < 16; ++c) s += W2l[o][c]*y1[c][j];
            a += W3l[o]*relu(s);
        }
        __builtin_nontemporal_store(relu(a), out + hbase + j);
    }
}

extern "C" void kernel_launch(void* const* d_in, const int* in_sizes, int n_in,
                              void* d_out, int out_size, void* d_ws, size_t ws_size,
                              hipStream_t stream) {
    const float* p  = (const float*)d_in[0];
    const float* q  = (const float*)d_in[1];
    const float* W1 = (const float*)d_in[2];
    const float* b1 = (const float*)d_in[3];
    const float* W2 = (const float*)d_in[4];
    const float* b2 = (const float*)d_in[5];
    const float* W3 = (const float*)d_in[6];
    const float* b3 = (const float*)d_in[7];
    float* out = (float*)d_out;

    int bBoundary = (OH + 255) / 256;        // 2680
    int blocks = NBI + bBoundary;            // 512 interior + boundary fill
    ham_fused<<<blocks, 256, 0, stream>>>(p, q, W1, b1, W2, b2, W3, b3, out);
}